// Round 8
// baseline (163.461 us; speedup 1.0000x reference)
//
#include <hip/hip_runtime.h>
#include <hip/hip_fp16.h>
#include <math.h>

// GraphConvolution (GCNII variant=True, residual=True), N=100k, E=1M, D=64.
//   agg[dst] += h[src] * edge_w
//   out = theta*([agg,i]@W) + (1-theta)*((1-alpha)*agg + alpha*i) + i
//
// R16: 3 dispatches, f16 pipeline, 1024 x 128-node bins end-to-end.
// R15 (156.0us, best): all our kernels below the 40.5us poison-fill line.
// spmm (~40us) is latency-bound: serial chain bucket-read -> LDS sort ->
// gather -> epilogue, paid per block x 1.53 scheduling rounds.
// R16 change (spmm only): PERSISTENT blocks (grid 512 = 2/CU exactly);
// next bin's 16KB bucket is DMA'd global->LDS via global_load_lds during
// the current bin's gather+epilogue. The loop-top __syncthreads() drains
// vmcnt (documented gfx950 barrier semantics) so no explicit waits are
// needed. Removes global latency from the sort critical path and drops
// loop-carried VGPRs (no ev0/ev1 registers held across phases).
//   convert:  h->f16, W frag-pack, padded-gcur zero        (R15 unchanged)
//   bin_fill: staged single-atomic-pass bin-sort, ~64B-run flush (R15)
//   spmm:     persistent: { sort from LDS raw | DMA-prefetch next | pair-
//             gather | MFMA epilogue } loop.

#define DFEAT 64
#define BINSZ 128        // nodes per bin
#define NBINS 1024       // physical; logical = ceil(N/128) = 782
#define CAP   2048       // slots per bucket (mean 1280, sigma ~36)
#define GPAD  16         // gcur stride in ints (64 B = 1 line per counter)
#define CHUNK 8192       // edges per bin_fill block
#define BTPB  1024       // bin_fill block (16 waves)
#define EPT   8          // edges per thread in bin_fill
#define SPB   1024       // spmm block (16 waves)
#define SGRID 512        // spmm persistent grid (2 blocks/CU)

#define ASTR  72         // agg16 row stride in ushorts (144 B = 9*16, aligned)

typedef unsigned long long u64;
typedef __attribute__((ext_vector_type(8))) _Float16 f16x8;
typedef __attribute__((ext_vector_type(4))) float f32x4;

__device__ inline unsigned h2u(__half2 h) {
    union { __half2 h; unsigned u; } c; c.h = h; return c.u;
}
__device__ inline __half2 u2h(unsigned u) {
    union { unsigned u; __half2 h; } c; c.u = u; return c.h;
}

// ---- phase 0: h->f16 + W frag-pack + padded gcur zero ----
__global__ __launch_bounds__(256) void convert_kernel(
    const float* __restrict__ h, const float* __restrict__ weight,
    ushort* __restrict__ h16, ushort* __restrict__ w16,
    int* __restrict__ gcur, int total4) {
    int gid = blockIdx.x * 256 + threadIdx.x;
    int nth = gridDim.x * 256;
    if (gid < NBINS * GPAD) gcur[gid] = 0;
    for (int i = gid; i < total4; i += nth) {
        float4 v = ((const float4*)h)[i];
        uint2 o;
        o.x = h2u(__floats2half2_rn(v.x, v.y));
        o.y = h2u(__floats2half2_rn(v.z, v.w));
        ((uint2*)h16)[i] = o;
    }
    // W -> frag-packed f16: w16[((c*4+s)*64+l)*8+j]
    //   = f16(W[s*32 + (l>>4)*8 + j][c*16 + (l&15)])   (layout R8-verified)
    if (gid < 8192) {
        int j = gid & 7, l = (gid >> 3) & 63, cs = gid >> 9;
        int c = cs >> 2, s = cs & 3, q = l >> 4, m = l & 15;
        w16[gid] = __half_as_ushort(
            __float2half_rn(weight[(s * 32 + q * 8 + j) * DFEAT + c * 16 + m]));
    }
}

// ---- phase 1: staged edge binning by dst>>7, coalesced ~64B-run flush ----
// Staged (u64): [63:48]=w16  [42:33]=bin(10)  [30:24]=dl(7)  [16:0]=src
// Bucket (u64): [47:32]=w16  [30:24]=dl(7)    [16:0]=src
__global__ __launch_bounds__(1024) void bin_fill_kernel(
    const int* __restrict__ e_src, const int* __restrict__ e_dst,
    const float* __restrict__ e_w, int* __restrict__ gcur,
    u64* __restrict__ bucket, int E) {
    __shared__ u64 staging[CHUNK];           // 64 KB
    __shared__ int hist[NBINS];              // 4 KB
    __shared__ ushort offs[NBINS];           // 2 KB
    __shared__ ushort gbase[NBINS];          // 2 KB
    __shared__ int wtot[16];                 //        -> ~72 KB

    int tid = threadIdx.x;
    int e0 = blockIdx.x * CHUNK;
    int cc = min(CHUNK, E - e0);

    hist[tid] = 0;
    __syncthreads();

    int bn[EPT], r[EPT];
    u64 pk[EPT];
#pragma unroll
    for (int j = 0; j < EPT; ++j) {
        int e = e0 + j * BTPB + tid;
        bn[j] = -1;
        if (e < E) {
            int d = e_dst[e];
            int src = e_src[e];
            ushort wb = __half_as_ushort(__float2half_rn(e_w[e]));
            bn[j] = d >> 7;
            pk[j] = ((u64)wb << 48) | ((u64)(unsigned)bn[j] << 33) |
                    ((u64)(unsigned)(d & 127) << 24) | (u64)(unsigned)src;
        }
    }
#pragma unroll
    for (int j = 0; j < EPT; ++j)
        if (bn[j] >= 0) r[j] = atomicAdd(&hist[bn[j]], 1);
    __syncthreads();

    // hierarchical exclusive scan of hist[1024]: 1 bin per thread;
    // wave shfl scan -> 16 wave totals -> wave0 scans totals.
    int lane = tid & 63, wv = tid >> 6;
    int c = hist[tid];
    int s = c;
#pragma unroll
    for (int ofs = 1; ofs < 64; ofs <<= 1) {
        int t = __shfl_up(s, ofs);
        if (lane >= ofs) s += t;
    }
    if (lane == 63) wtot[wv] = s;
    __syncthreads();
    if (tid < 64) {       // wave 0: scan 16 totals, broadcast via LDS
        int v = (tid < 16) ? wtot[tid] : 0;
        int sw = v;
#pragma unroll
        for (int ofs = 1; ofs < 16; ofs <<= 1) {
            int t = __shfl_up(sw, ofs);
            if (tid >= ofs) sw += t;
        }
        if (tid < 16) ((int*)wtot)[tid] = sw - v;   // reuse wtot as wexcl
    }
    __syncthreads();
    int excl = wtot[wv] + (s - c);
    offs[tid] = (ushort)excl;
    __syncthreads();

    // reservation atomic (global, long latency) interleaved with LDS scatter
    {
        int g = c ? atomicAdd(&gcur[tid * GPAD], c) : 0;
        gbase[tid] = (ushort)min(g, CAP);
    }
#pragma unroll
    for (int j = 0; j < EPT; ++j)
        if (bn[j] >= 0) staging[(int)offs[bn[j]] + r[j]] = pk[j];
    __syncthreads();

    // flush: bin-contiguous runs (~8 edges = 64B) -> contiguous global slots
#pragma unroll
    for (int j = 0; j < EPT; ++j) {
        int p = j * BTPB + tid;
        if (p < cc) {
            u64 e = staging[p];
            int bin = (int)((e >> 33) & 1023);
            int pos = (int)gbase[bin] + (p - (int)offs[bin]);
            if (pos < CAP) {
                bucket[(size_t)bin * CAP + pos] =
                    ((e >> 48) << 32) | (e & 0x7FFFFFFFull);
            }
        }
    }
}

// async DMA of one bin's full 16KB bucket into LDS raw buffer.
// dest = wave-uniform base + lane*16 (linear); source per-lane.
__device__ inline void dma_bucket(const u64* bk, void* rawbase, int tid) {
    const char* g = (const char*)bk + (size_t)tid * 16;
    char* l = (char*)rawbase + ((tid >> 6) << 10);
    __builtin_amdgcn_global_load_lds(
        (const __attribute__((address_space(1))) void*)g,
        (__attribute__((address_space(3))) void*)l, 16, 0, 0);
}

// ---- phase 2: persistent { sort | prefetch | pair-gather | epilogue } ----
// 1024 threads (16 waves), ~52 KB LDS -> 2 blocks/CU, grid 512.
// Wave wv gathers nodes [wv*8, wv*8+8) as 4 pairs: lanes 0-31 node A,
// lanes 32-63 node B, 4 edge-slots/node/step, uint4 loads (8 feats/lane).
__global__ __launch_bounds__(1024) void spmm_kernel(
    const ushort* __restrict__ h16, const u64* __restrict__ bucket,
    const int* __restrict__ gcur, const ushort* __restrict__ w16,
    const float* __restrict__ ifeat,
    const float* __restrict__ lamda_p, const float* __restrict__ alpha_p,
    const int* __restrict__ layer_p,
    float* __restrict__ out, int nbins, int N) {
    __shared__ __align__(16) u64 raw[CAP];                // 16 KB (DMA dest)
    __shared__ u64 sorted[CAP];                           // 16 KB
    __shared__ __align__(16) ushort agg16[BINSZ * ASTR];  // 18 KB (f16 agg)
    __shared__ int hist[BINSZ], start[BINSZ];             // 1 KB
    __shared__ int wsum[2];

    int tid = threadIdx.x;
    int lane = tid & 63, wv = tid >> 6;
    int g8 = lane >> 3;        // 0..7
    int m8 = lane & 7;         // feature block: halves m8*8..m8*8+7
    int hf = g8 >> 2;          // 0: node A (lanes 0-31), 1: node B
    int gs = g8 & 3;           // edge-slot subgroup within node
    int m = lane & 15, q = lane >> 4;
    int t = wv >> 1, ch = wv & 1;

    float alf = alpha_p[0];
    float theta = fminf(1.0f, logf(lamda_p[0] / (float)layer_p[0] + 1.0f));

    int bin = blockIdx.x;
    if (bin >= nbins) return;
    int cnt = min(gcur[bin << 4], CAP);
    dma_bucket(bucket + (size_t)bin * CAP, raw, tid);   // prefetch bin 0

    for (;;) {
        int base = bin << 7;

        // ---- sort phase (raw guaranteed complete after barrier drain) ----
        if (tid < BINSZ) hist[tid] = 0;
        __syncthreads();   // drains vmcnt -> DMA done; orders hist zero

        u64 ev0 = raw[tid];
        u64 ev1 = raw[tid + SPB];
        int dl0 = (tid < cnt) ? (int)((ev0 >> 24) & 127) : -1;
        int dl1 = (tid + SPB < cnt) ? (int)((ev1 >> 24) & 127) : -1;
        int r0 = 0, r1 = 0;
        if (dl0 >= 0) r0 = atomicAdd(&hist[dl0], 1);
        if (dl1 >= 0) r1 = atomicAdd(&hist[dl1], 1);
        __syncthreads();

        // 2-wave shfl exclusive scan over 128 counters
        int sv = 0, vv = 0;
        if (tid < 128) {
            vv = hist[tid];
            sv = vv;
#pragma unroll
            for (int ofs = 1; ofs < 64; ofs <<= 1) {
                int tt = __shfl_up(sv, ofs);
                if (lane >= ofs) sv += tt;
            }
            if (lane == 63) wsum[tid >> 6] = sv;
        }
        __syncthreads();
        if (tid < 128) start[tid] = sv - vv + ((tid >= 64) ? wsum[0] : 0);
        __syncthreads();

        // scatter into node-sorted LDS (unique slot = start + rank)
        if (dl0 >= 0) sorted[start[dl0] + r0] = ev0;
        if (dl1 >= 0) sorted[start[dl1] + r1] = ev1;
        if (cnt == 0 && tid == 0) sorted[0] = 0;  // dummy for clamped reads
        __syncthreads();   // raw reads done -> safe to DMA-overwrite below

        // ---- prefetch next bin (overlaps gather + epilogue) ----
        int nbin = bin + SGRID;
        int ncnt = 0;
        if (nbin < nbins) {
            ncnt = min(gcur[nbin << 4], CAP);
            dma_bucket(bucket + (size_t)nbin * CAP, raw, tid);
        }

        // HOISTED ifeat frag loads (overlap with gather)
        f16x8 faI[2];
        {
            const float* ip =
                ifeat + (size_t)min(base + t * 16 + m, N - 1) * DFEAT;
#pragma unroll
            for (int s = 0; s < 2; ++s) {
                float4 v0 = *(const float4*)(ip + s * 32 + q * 8);
                float4 v1 = *(const float4*)(ip + s * 32 + q * 8 + 4);
                f16x8 tt;
                tt[0] = (_Float16)v0.x; tt[1] = (_Float16)v0.y;
                tt[2] = (_Float16)v0.z; tt[3] = (_Float16)v0.w;
                tt[4] = (_Float16)v1.x; tt[5] = (_Float16)v1.y;
                tt[6] = (_Float16)v1.z; tt[7] = (_Float16)v1.w;
                faI[s] = tt;
            }
        }

        // ---- pair-gather: 4 slots/node/s-step, 16 slots/node/iter ----
        for (int kp = 0; kp < 4; ++kp) {
            int nl = (wv << 3) + (kp << 1) + hf;
            int d = hist[nl];
            int b0 = start[nl];
            int hi = (d > 0) ? (b0 + d - 1) : 0;
            __half2 a0 = u2h(0u), a1 = u2h(0u), a2 = u2h(0u), a3 = u2h(0u);
            for (int t0 = 0; t0 < d; t0 += 16) {
#pragma unroll
                for (int s = 0; s < 4; ++s) {
                    int idx = t0 + (s << 2) + gs;
                    u64 e = sorted[min(b0 + idx, hi)];
                    ushort wb = (idx < d) ? (ushort)(e >> 32) : (ushort)0;
                    __half2 w2 = __half2half2(__ushort_as_half(wb));
                    unsigned src = ((unsigned)e) & 0x1FFFFu;
                    uint4 hv =
                        *(const uint4*)(h16 + ((size_t)src << 6) + (m8 << 3));
                    a0 = __hfma2(w2, u2h(hv.x), a0);
                    a1 = __hfma2(w2, u2h(hv.y), a1);
                    a2 = __hfma2(w2, u2h(hv.z), a2);
                    a3 = __hfma2(w2, u2h(hv.w), a3);
                }
            }
            // reduce across 4 slot-groups (xor 8,16 stay within each half)
            a0 = __hadd2(a0, u2h((unsigned)__shfl_xor((int)h2u(a0), 8)));
            a1 = __hadd2(a1, u2h((unsigned)__shfl_xor((int)h2u(a1), 8)));
            a2 = __hadd2(a2, u2h((unsigned)__shfl_xor((int)h2u(a2), 8)));
            a3 = __hadd2(a3, u2h((unsigned)__shfl_xor((int)h2u(a3), 8)));
            a0 = __hadd2(a0, u2h((unsigned)__shfl_xor((int)h2u(a0), 16)));
            a1 = __hadd2(a1, u2h((unsigned)__shfl_xor((int)h2u(a1), 16)));
            a2 = __hadd2(a2, u2h((unsigned)__shfl_xor((int)h2u(a2), 16)));
            a3 = __hadd2(a3, u2h((unsigned)__shfl_xor((int)h2u(a3), 16)));
            if (gs == 0) {
                uint4 o;
                o.x = h2u(a0); o.y = h2u(a1); o.z = h2u(a2); o.w = h2u(a3);
                *(uint4*)(agg16 + nl * ASTR + (m8 << 3)) = o;
            }
        }
        __syncthreads();   // epilogue tile rows span multiple waves' output

        // ---- fused epilogue: tile t (16 rows), col-tiles {2ch, 2ch+1} ----
        f16x8 faA[2];
#pragma unroll
        for (int s = 0; s < 2; ++s)
            faA[s] =
                *(const f16x8*)(agg16 + (t * 16 + m) * ASTR + s * 32 + q * 8);

        f32x4 acc[2] = {{0.f, 0.f, 0.f, 0.f}, {0.f, 0.f, 0.f, 0.f}};
#pragma unroll
        for (int ci = 0; ci < 2; ++ci) {
            int c = ch * 2 + ci;
#pragma unroll
            for (int s = 0; s < 2; ++s) {
                f16x8 bA = *(const f16x8*)(w16 + ((c * 4 + s) * 64 + lane) * 8);
                acc[ci] = __builtin_amdgcn_mfma_f32_16x16x32_f16(
                    faA[s], bA, acc[ci], 0, 0, 0);
                f16x8 bI =
                    *(const f16x8*)(w16 + ((c * 4 + s + 2) * 64 + lane) * 8);
                acc[ci] = __builtin_amdgcn_mfma_f32_16x16x32_f16(
                    faI[s], bI, acc[ci], 0, 0, 0);
            }
        }

        // mix + residual + store (C/D: row = t*16 + q*4 + r, col = c*16 + m)
#pragma unroll
        for (int ci = 0; ci < 2; ++ci) {
            int c = ch * 2 + ci;
            int col = c * 16 + m;
#pragma unroll
            for (int r = 0; r < 4; ++r) {
                int rowL = t * 16 + q * 4 + r;
                int row = base + rowL;
                if (row < N) {
                    float av = __half2float(
                        *(const __half*)(agg16 + rowL * ASTR + col));
                    float iv = ifeat[(size_t)row * DFEAT + col];
                    out[(size_t)row * DFEAT + col] =
                        theta * acc[ci][r] +
                        (1.f - theta) * ((1.f - alf) * av + alf * iv) + iv;
                }
            }
        }

        if (nbin >= nbins) break;
        bin = nbin;
        cnt = ncnt;
    }
}

extern "C" void kernel_launch(void* const* d_in, const int* in_sizes, int n_in,
                              void* d_out, int out_size, void* d_ws, size_t ws_size,
                              hipStream_t stream) {
    const float* h       = (const float*)d_in[0];
    const float* ifeat   = (const float*)d_in[1];
    const float* weight  = (const float*)d_in[2];
    const float* edge_w  = (const float*)d_in[3];
    const float* lamda_p = (const float*)d_in[4];
    const float* alpha_p = (const float*)d_in[5];
    const int*   e_src   = (const int*)d_in[6];
    const int*   e_dst   = (const int*)d_in[7];
    const int*   layer_p = (const int*)d_in[8];
    float* out = (float*)d_out;

    int N = in_sizes[0] / DFEAT;       // 100000
    int E = in_sizes[3];               // 1000000
    int nbins = (N + BINSZ - 1) >> 7;  // 782

    // ws: gcur[1024*16] (64KB) | bucket 16.78MB | h16 12.8MB | w16 16KB
    int* gcur = (int*)d_ws;
    u64* bucket = (u64*)((char*)d_ws + (size_t)NBINS * GPAD * sizeof(int));
    ushort* h16 = (ushort*)((char*)bucket + (size_t)NBINS * CAP * sizeof(u64));
    ushort* w16 = h16 + (size_t)N * DFEAT;

    int total4 = N * DFEAT / 4;
    convert_kernel<<<2048, 256, 0, stream>>>(h, weight, h16, w16, gcur, total4);

    bin_fill_kernel<<<(E + CHUNK - 1) / CHUNK, BTPB, 0, stream>>>(
        e_src, e_dst, edge_w, gcur, bucket, E);

    int sgrid = nbins < SGRID ? nbins : SGRID;
    spmm_kernel<<<sgrid, SPB, 0, stream>>>(
        h16, bucket, gcur, w16, ifeat, lamda_p, alpha_p, layer_p, out,
        nbins, N);
}

// Round 9
// 159.865 us; speedup vs baseline: 1.0225x; 1.0225x over previous
//
#include <hip/hip_runtime.h>
#include <hip/hip_fp16.h>
#include <math.h>

// GraphConvolution (GCNII variant=True, residual=True), N=100k, E=1M, D=64.
//   agg[dst] += h[src] * edge_w
//   out = theta*([agg,i]@W) + (1-theta)*((1-alpha)*agg + alpha*i) + i
//
// R17: 3 dispatches, f16 pipeline, 1024 x 128-node bins end-to-end.
// LESSON (R16, spmm 40.5->48.5): persistent+DMA-prefetch regressed -- VGPR
// 32->64, LDS 36->52.7KB (occ 31%), FETCH +4MB (DMA pulls full CAP), and
// 65% of bins get no overlap (first-bin latency still serial). spmm
// REVERTED to R15's exact version (best measured, <=40.5us).
// R17 change (bin_fill only): CHUNK 8192->4096 (EPT 4) => 245 blocks
// (~1/CU instead of 123 = half the CUs idle). Keeps 128-node bins and
// ~4-edge coalesced flush runs (R9-proven). Reservation atomics double
// to 250K but stay padded (245 RMWs/line, far from R10's 4900/line).
//   convert:  h->f16, W frag-pack, padded-gcur zero        (R15 unchanged)
//   bin_fill: staged single-atomic-pass bin-sort, 245 blocks, runs ~4.
//   spmm:     R15 exact: 1024 thr / 128-node bin, single-pass counting
//             sort, pair-gather, MFMA epilogue, ifeat frags hoisted.

#define DFEAT 64
#define BINSZ 128        // nodes per bin
#define NBINS 1024       // physical; logical = ceil(N/128) = 782
#define CAP   2048       // slots per bucket (mean 1280, sigma ~36)
#define GPAD  16         // gcur stride in ints (64 B = 1 line per counter)
#define CHUNK 4096       // edges per bin_fill block
#define BTPB  1024       // bin_fill block (16 waves)
#define EPT   4          // edges per thread in bin_fill
#define SPB   1024       // spmm block (16 waves)

#define ASTR  72         // agg16 row stride in ushorts (144 B = 9*16, aligned)

typedef unsigned long long u64;
typedef __attribute__((ext_vector_type(8))) _Float16 f16x8;
typedef __attribute__((ext_vector_type(4))) float f32x4;

__device__ inline unsigned h2u(__half2 h) {
    union { __half2 h; unsigned u; } c; c.h = h; return c.u;
}
__device__ inline __half2 u2h(unsigned u) {
    union { unsigned u; __half2 h; } c; c.u = u; return c.h;
}

// ---- phase 0: h->f16 + W frag-pack + padded gcur zero ----
__global__ __launch_bounds__(256) void convert_kernel(
    const float* __restrict__ h, const float* __restrict__ weight,
    ushort* __restrict__ h16, ushort* __restrict__ w16,
    int* __restrict__ gcur, int total4) {
    int gid = blockIdx.x * 256 + threadIdx.x;
    int nth = gridDim.x * 256;
    if (gid < NBINS * GPAD) gcur[gid] = 0;
    for (int i = gid; i < total4; i += nth) {
        float4 v = ((const float4*)h)[i];
        uint2 o;
        o.x = h2u(__floats2half2_rn(v.x, v.y));
        o.y = h2u(__floats2half2_rn(v.z, v.w));
        ((uint2*)h16)[i] = o;
    }
    // W -> frag-packed f16: w16[((c*4+s)*64+l)*8+j]
    //   = f16(W[s*32 + (l>>4)*8 + j][c*16 + (l&15)])   (layout R8-verified)
    if (gid < 8192) {
        int j = gid & 7, l = (gid >> 3) & 63, cs = gid >> 9;
        int c = cs >> 2, s = cs & 3, q = l >> 4, m = l & 15;
        w16[gid] = __half_as_ushort(
            __float2half_rn(weight[(s * 32 + q * 8 + j) * DFEAT + c * 16 + m]));
    }
}

// ---- phase 1: staged edge binning by dst>>7, coalesced ~4-edge runs ----
// Staged (u64): [63:48]=w16  [42:33]=bin(10)  [30:24]=dl(7)  [16:0]=src
// Bucket (u64): [47:32]=w16  [30:24]=dl(7)    [16:0]=src
__global__ __launch_bounds__(1024) void bin_fill_kernel(
    const int* __restrict__ e_src, const int* __restrict__ e_dst,
    const float* __restrict__ e_w, int* __restrict__ gcur,
    u64* __restrict__ bucket, int E) {
    __shared__ u64 staging[CHUNK];           // 32 KB
    __shared__ int hist[NBINS];              // 4 KB
    __shared__ ushort offs[NBINS];           // 2 KB
    __shared__ ushort gbase[NBINS];          // 2 KB
    __shared__ int wtot[16];                 //        -> ~40 KB

    int tid = threadIdx.x;
    int e0 = blockIdx.x * CHUNK;
    int cc = min(CHUNK, E - e0);

    hist[tid] = 0;
    __syncthreads();

    int bn[EPT], r[EPT];
    u64 pk[EPT];
#pragma unroll
    for (int j = 0; j < EPT; ++j) {
        int e = e0 + j * BTPB + tid;
        bn[j] = -1;
        if (e < E) {
            int d = e_dst[e];
            int src = e_src[e];
            ushort wb = __half_as_ushort(__float2half_rn(e_w[e]));
            bn[j] = d >> 7;
            pk[j] = ((u64)wb << 48) | ((u64)(unsigned)bn[j] << 33) |
                    ((u64)(unsigned)(d & 127) << 24) | (u64)(unsigned)src;
        }
    }
#pragma unroll
    for (int j = 0; j < EPT; ++j)
        if (bn[j] >= 0) r[j] = atomicAdd(&hist[bn[j]], 1);
    __syncthreads();

    // hierarchical exclusive scan of hist[1024]: 1 bin per thread;
    // wave shfl scan -> 16 wave totals -> wave0 scans totals.
    int lane = tid & 63, wv = tid >> 6;
    int c = hist[tid];
    int s = c;
#pragma unroll
    for (int ofs = 1; ofs < 64; ofs <<= 1) {
        int t = __shfl_up(s, ofs);
        if (lane >= ofs) s += t;
    }
    if (lane == 63) wtot[wv] = s;
    __syncthreads();
    if (tid < 64) {       // wave 0: scan 16 totals, broadcast via LDS
        int v = (tid < 16) ? wtot[tid] : 0;
        int sw = v;
#pragma unroll
        for (int ofs = 1; ofs < 16; ofs <<= 1) {
            int t = __shfl_up(sw, ofs);
            if (tid >= ofs) sw += t;
        }
        if (tid < 16) ((int*)wtot)[tid] = sw - v;   // reuse wtot as wexcl
    }
    __syncthreads();
    int excl = wtot[wv] + (s - c);
    offs[tid] = (ushort)excl;
    __syncthreads();

    // reservation atomic (global, long latency) interleaved with LDS scatter
    {
        int g = c ? atomicAdd(&gcur[tid * GPAD], c) : 0;
        gbase[tid] = (ushort)min(g, CAP);
    }
#pragma unroll
    for (int j = 0; j < EPT; ++j)
        if (bn[j] >= 0) staging[(int)offs[bn[j]] + r[j]] = pk[j];
    __syncthreads();

    // flush: bin-contiguous runs (~4 edges = 32B) -> contiguous global slots
#pragma unroll
    for (int j = 0; j < EPT; ++j) {
        int p = j * BTPB + tid;
        if (p < cc) {
            u64 e = staging[p];
            int bin = (int)((e >> 33) & 1023);
            int pos = (int)gbase[bin] + (p - (int)offs[bin]);
            if (pos < CAP) {
                bucket[(size_t)bin * CAP + pos] =
                    ((e >> 48) << 32) | (e & 0x7FFFFFFFull);
            }
        }
    }
}

// ---- phase 2: single-pass counting sort + pair-gather + MFMA epilogue ----
// 1024 threads (16 waves), ~36 KB LDS -> 2 blocks/CU (32 waves), grid 782.
// Wave wv gathers nodes [wv*8, wv*8+8) as 4 pairs: lanes 0-31 node A,
// lanes 32-63 node B, 4 edge-slots/node/step, uint4 loads (8 feats/lane).
// (R15 exact -- best measured config.)
__global__ __launch_bounds__(1024) void spmm_kernel(
    const ushort* __restrict__ h16, const u64* __restrict__ bucket,
    const int* __restrict__ gcur, const ushort* __restrict__ w16,
    const float* __restrict__ ifeat,
    const float* __restrict__ lamda_p, const float* __restrict__ alpha_p,
    const int* __restrict__ layer_p,
    float* __restrict__ out, int N) {
    __shared__ u64 sorted[CAP];                           // 16 KB
    __shared__ __align__(16) ushort agg16[BINSZ * ASTR];  // 18 KB (f16 agg)
    __shared__ int hist[BINSZ], start[BINSZ];             // 1 KB
    __shared__ int wsum[2];

    int tid = threadIdx.x;
    int bin = blockIdx.x;
    int base = bin << 7;
    int cnt = min(gcur[bin << 4], CAP);
    const u64* bk = bucket + (size_t)bin * CAP;

    if (tid < BINSZ) hist[tid] = 0;
    __syncthreads();

    // single bucket pass: stage entries in regs, rank via atomic-return
    u64 ev0 = 0, ev1 = 0;
    int dl0 = -1, dl1 = -1, r0 = 0, r1 = 0;
    if (tid < cnt) { ev0 = bk[tid]; dl0 = (int)((ev0 >> 24) & 127); }
    if (tid + SPB < cnt) { ev1 = bk[tid + SPB]; dl1 = (int)((ev1 >> 24) & 127); }
    if (dl0 >= 0) r0 = atomicAdd(&hist[dl0], 1);
    if (dl1 >= 0) r1 = atomicAdd(&hist[dl1], 1);
    __syncthreads();

    int lane = tid & 63, wv = tid >> 6;

    // 2-wave shfl exclusive scan over 128 counters
    int sv = 0, vv = 0;
    if (tid < 128) {
        vv = hist[tid];
        sv = vv;
#pragma unroll
        for (int ofs = 1; ofs < 64; ofs <<= 1) {
            int t = __shfl_up(sv, ofs);
            if (lane >= ofs) sv += t;
        }
        if (lane == 63) wsum[tid >> 6] = sv;
    }
    __syncthreads();
    if (tid < 128) start[tid] = sv - vv + ((tid >= 64) ? wsum[0] : 0);
    __syncthreads();

    // scatter into node-sorted LDS (unique slot = start + rank)
    if (dl0 >= 0) sorted[start[dl0] + r0] = ev0;
    if (dl1 >= 0) sorted[start[dl1] + r1] = ev1;
    if (cnt == 0 && tid == 0) sorted[0] = 0;  // finite dummy for clamped reads
    __syncthreads();

    int g8 = lane >> 3;        // 0..7
    int m8 = lane & 7;         // feature block: halves m8*8..m8*8+7
    int hf = g8 >> 2;          // 0: node A (lanes 0-31), 1: node B
    int gs = g8 & 3;           // edge-slot subgroup within node

    // epilogue indices + HOISTED ifeat frag loads (overlap with gather)
    int m = lane & 15, q = lane >> 4;
    int t = wv >> 1, ch = wv & 1;
    f16x8 faI[2];
    {
        const float* ip = ifeat + (size_t)min(base + t * 16 + m, N - 1) * DFEAT;
#pragma unroll
        for (int s = 0; s < 2; ++s) {
            float4 v0 = *(const float4*)(ip + s * 32 + q * 8);
            float4 v1 = *(const float4*)(ip + s * 32 + q * 8 + 4);
            f16x8 tt;
            tt[0] = (_Float16)v0.x; tt[1] = (_Float16)v0.y;
            tt[2] = (_Float16)v0.z; tt[3] = (_Float16)v0.w;
            tt[4] = (_Float16)v1.x; tt[5] = (_Float16)v1.y;
            tt[6] = (_Float16)v1.z; tt[7] = (_Float16)v1.w;
            faI[s] = tt;
        }
    }

    // pair-gather: 4 slots/node/s-step, s unrolled 4 -> 16 slots/node/iter
    for (int kp = 0; kp < 4; ++kp) {
        int nl = (wv << 3) + (kp << 1) + hf;
        int d = hist[nl];
        int b0 = start[nl];
        int hi = (d > 0) ? (b0 + d - 1) : 0;   // clamp target always init'd
        __half2 a0 = u2h(0u), a1 = u2h(0u), a2 = u2h(0u), a3 = u2h(0u);
        for (int t0 = 0; t0 < d; t0 += 16) {
#pragma unroll
            for (int s = 0; s < 4; ++s) {
                int idx = t0 + (s << 2) + gs;
                u64 e = sorted[min(b0 + idx, hi)];
                ushort wb = (idx < d) ? (ushort)(e >> 32) : (ushort)0;
                __half2 w2 = __half2half2(__ushort_as_half(wb));
                unsigned src = ((unsigned)e) & 0x1FFFFu;
                uint4 hv = *(const uint4*)(h16 + ((size_t)src << 6) + (m8 << 3));
                a0 = __hfma2(w2, u2h(hv.x), a0);
                a1 = __hfma2(w2, u2h(hv.y), a1);
                a2 = __hfma2(w2, u2h(hv.z), a2);
                a3 = __hfma2(w2, u2h(hv.w), a3);
            }
        }
        // reduce across the 4 slot-groups (xor 8,16 stay within each half)
        a0 = __hadd2(a0, u2h((unsigned)__shfl_xor((int)h2u(a0), 8)));
        a1 = __hadd2(a1, u2h((unsigned)__shfl_xor((int)h2u(a1), 8)));
        a2 = __hadd2(a2, u2h((unsigned)__shfl_xor((int)h2u(a2), 8)));
        a3 = __hadd2(a3, u2h((unsigned)__shfl_xor((int)h2u(a3), 8)));
        a0 = __hadd2(a0, u2h((unsigned)__shfl_xor((int)h2u(a0), 16)));
        a1 = __hadd2(a1, u2h((unsigned)__shfl_xor((int)h2u(a1), 16)));
        a2 = __hadd2(a2, u2h((unsigned)__shfl_xor((int)h2u(a2), 16)));
        a3 = __hadd2(a3, u2h((unsigned)__shfl_xor((int)h2u(a3), 16)));
        if (gs == 0) {
            uint4 o;
            o.x = h2u(a0); o.y = h2u(a1); o.z = h2u(a2); o.w = h2u(a3);
            *(uint4*)(agg16 + nl * ASTR + (m8 << 3)) = o;
        }
    }
    __syncthreads();   // epilogue tile rows span multiple waves' output

    // fused epilogue: tile t = wv>>1 (16 rows), col-tiles {2ch, 2ch+1}
    float alf = alpha_p[0];
    float theta = fminf(1.0f, logf(lamda_p[0] / (float)layer_p[0] + 1.0f));

    f16x8 faA[2];
#pragma unroll
    for (int s = 0; s < 2; ++s)
        faA[s] = *(const f16x8*)(agg16 + (t * 16 + m) * ASTR + s * 32 + q * 8);

    f32x4 acc[2] = {{0.f, 0.f, 0.f, 0.f}, {0.f, 0.f, 0.f, 0.f}};
#pragma unroll
    for (int ci = 0; ci < 2; ++ci) {
        int c = ch * 2 + ci;
#pragma unroll
        for (int s = 0; s < 2; ++s) {
            f16x8 bA = *(const f16x8*)(w16 + ((c * 4 + s) * 64 + lane) * 8);
            acc[ci] = __builtin_amdgcn_mfma_f32_16x16x32_f16(faA[s], bA, acc[ci], 0, 0, 0);
            f16x8 bI = *(const f16x8*)(w16 + ((c * 4 + s + 2) * 64 + lane) * 8);
            acc[ci] = __builtin_amdgcn_mfma_f32_16x16x32_f16(faI[s], bI, acc[ci], 0, 0, 0);
        }
    }

    // mix + residual + store (C/D: row = t*16 + q*4 + r, col = c*16 + m)
#pragma unroll
    for (int ci = 0; ci < 2; ++ci) {
        int c = ch * 2 + ci;
        int col = c * 16 + m;
#pragma unroll
        for (int r = 0; r < 4; ++r) {
            int rowL = t * 16 + q * 4 + r;
            int row = base + rowL;
            if (row < N) {
                float av = __half2float(
                    *(const __half*)(agg16 + rowL * ASTR + col));
                float iv = ifeat[(size_t)row * DFEAT + col];
                out[(size_t)row * DFEAT + col] =
                    theta * acc[ci][r] +
                    (1.f - theta) * ((1.f - alf) * av + alf * iv) + iv;
            }
        }
    }
}

extern "C" void kernel_launch(void* const* d_in, const int* in_sizes, int n_in,
                              void* d_out, int out_size, void* d_ws, size_t ws_size,
                              hipStream_t stream) {
    const float* h       = (const float*)d_in[0];
    const float* ifeat   = (const float*)d_in[1];
    const float* weight  = (const float*)d_in[2];
    const float* edge_w  = (const float*)d_in[3];
    const float* lamda_p = (const float*)d_in[4];
    const float* alpha_p = (const float*)d_in[5];
    const int*   e_src   = (const int*)d_in[6];
    const int*   e_dst   = (const int*)d_in[7];
    const int*   layer_p = (const int*)d_in[8];
    float* out = (float*)d_out;

    int N = in_sizes[0] / DFEAT;       // 100000
    int E = in_sizes[3];               // 1000000
    int nbins = (N + BINSZ - 1) >> 7;  // 782

    // ws: gcur[1024*16] (64KB) | bucket 16.78MB | h16 12.8MB | w16 16KB
    int* gcur = (int*)d_ws;
    u64* bucket = (u64*)((char*)d_ws + (size_t)NBINS * GPAD * sizeof(int));
    ushort* h16 = (ushort*)((char*)bucket + (size_t)NBINS * CAP * sizeof(u64));
    ushort* w16 = h16 + (size_t)N * DFEAT;

    int total4 = N * DFEAT / 4;
    convert_kernel<<<2048, 256, 0, stream>>>(h, weight, h16, w16, gcur, total4);

    bin_fill_kernel<<<(E + CHUNK - 1) / CHUNK, BTPB, 0, stream>>>(
        e_src, e_dst, edge_w, gcur, bucket, E);

    spmm_kernel<<<nbins, SPB, 0, stream>>>(
        h16, bucket, gcur, w16, ifeat, lamda_p, alpha_p, layer_p, out, N);
}

// Round 10
// 151.590 us; speedup vs baseline: 1.0783x; 1.0546x over previous
//
#include <hip/hip_runtime.h>
#include <hip/hip_fp16.h>
#include <math.h>

// GraphConvolution (GCNII variant=True, residual=True), N=100k, E=1M, D=64.
//   agg[dst] += h[src] * edge_w
//   out = theta*([agg,i]@W) + (1-theta)*((1-alpha)*agg + alpha*i) + i
//
// R18: 3 dispatches, f16 pipeline, 1024 x 128-node bins.
// KEY CHANGE (algebraic): the mix+residual terms are linear in agg and i,
// so they FOLD INTO W exactly:
//   W'[0:64]   = theta*W[0:64]   + (1-theta)(1-alpha)*I
//   W'[64:128] = theta*W[64:128] + ((1-theta)*alpha + 1)*I
//   out = [agg, i] @ W'
// convert_kernel bakes theta/alpha/diagonals into the f16 W pack. spmm's
// epilogue loses the 26MB f32 ifeat mix-read, the agg16 LDS re-read, and
// all mix VALU -- store is straight from MFMA acc.
// LESSON (R17): CHUNK 4096 bought nothing; identical spmm code measured
// 40.5 vs 43.6 across sessions (~±5% noise). bin_fill reverted to R15's
// CHUNK 8192. spmm otherwise R15-exact (best measured).
//   convert:  h->f16, W' frag-pack (theta/alpha folded), padded-gcur zero.
//   bin_fill: staged single-atomic-pass bin-sort, ~64B-run flush (R15).
//   spmm:     single-pass counting sort, pair-gather, MFMA, direct store.

#define DFEAT 64
#define BINSZ 128        // nodes per bin
#define NBINS 1024       // physical; logical = ceil(N/128) = 782
#define CAP   2048       // slots per bucket (mean 1280, sigma ~36)
#define GPAD  16         // gcur stride in ints (64 B = 1 line per counter)
#define CHUNK 8192       // edges per bin_fill block
#define BTPB  1024       // bin_fill block (16 waves)
#define EPT   8          // edges per thread in bin_fill
#define SPB   1024       // spmm block (16 waves)

#define ASTR  72         // agg16 row stride in ushorts (144 B = 9*16, aligned)

typedef unsigned long long u64;
typedef __attribute__((ext_vector_type(8))) _Float16 f16x8;
typedef __attribute__((ext_vector_type(4))) float f32x4;

__device__ inline unsigned h2u(__half2 h) {
    union { __half2 h; unsigned u; } c; c.h = h; return c.u;
}
__device__ inline __half2 u2h(unsigned u) {
    union { unsigned u; __half2 h; } c; c.u = u; return c.h;
}

// ---- phase 0: h->f16 + W' frag-pack (mix folded) + padded gcur zero ----
__global__ __launch_bounds__(256) void convert_kernel(
    const float* __restrict__ h, const float* __restrict__ weight,
    const float* __restrict__ lamda_p, const float* __restrict__ alpha_p,
    const int* __restrict__ layer_p,
    ushort* __restrict__ h16, ushort* __restrict__ w16,
    int* __restrict__ gcur, int total4) {
    int gid = blockIdx.x * 256 + threadIdx.x;
    int nth = gridDim.x * 256;
    if (gid < NBINS * GPAD) gcur[gid] = 0;
    for (int i = gid; i < total4; i += nth) {
        float4 v = ((const float4*)h)[i];
        uint2 o;
        o.x = h2u(__floats2half2_rn(v.x, v.y));
        o.y = h2u(__floats2half2_rn(v.z, v.w));
        ((uint2*)h16)[i] = o;
    }
    // W' -> frag-packed f16: w16[((c*4+s)*64+l)*8+j]
    //   = f16(theta*W[rw][cl] + diag), rw = s*32+(l>>4)*8+j (0..127; rows
    //   64..127 = i half), cl = c*16+(l&15). Diagonals:
    //   rw<64,  rw==cl:    +(1-theta)(1-alpha)
    //   rw>=64, rw-64==cl: +(1-theta)*alpha + 1      (residual folded)
    if (gid < 8192) {
        int j = gid & 7, l = (gid >> 3) & 63, cs = gid >> 9;
        int c = cs >> 2, s = cs & 3, q = l >> 4, m = l & 15;
        int rw = s * 32 + q * 8 + j;
        int cl = c * 16 + m;
        float theta = fminf(1.0f, logf(lamda_p[0] / (float)layer_p[0] + 1.0f));
        float alf = alpha_p[0];
        float v = theta * weight[rw * DFEAT + cl];
        if (rw < 64) {
            if (rw == cl) v += (1.f - theta) * (1.f - alf);
        } else {
            if (rw - 64 == cl) v += (1.f - theta) * alf + 1.f;
        }
        w16[gid] = __half_as_ushort(__float2half_rn(v));
    }
}

// ---- phase 1: staged edge binning by dst>>7, coalesced ~64B-run flush ----
// Staged (u64): [63:48]=w16  [42:33]=bin(10)  [30:24]=dl(7)  [16:0]=src
// Bucket (u64): [47:32]=w16  [30:24]=dl(7)    [16:0]=src
__global__ __launch_bounds__(1024) void bin_fill_kernel(
    const int* __restrict__ e_src, const int* __restrict__ e_dst,
    const float* __restrict__ e_w, int* __restrict__ gcur,
    u64* __restrict__ bucket, int E) {
    __shared__ u64 staging[CHUNK];           // 64 KB
    __shared__ int hist[NBINS];              // 4 KB
    __shared__ ushort offs[NBINS];           // 2 KB
    __shared__ ushort gbase[NBINS];          // 2 KB
    __shared__ int wtot[16];                 //        -> ~72 KB

    int tid = threadIdx.x;
    int e0 = blockIdx.x * CHUNK;
    int cc = min(CHUNK, E - e0);

    hist[tid] = 0;
    __syncthreads();

    int bn[EPT], r[EPT];
    u64 pk[EPT];
#pragma unroll
    for (int j = 0; j < EPT; ++j) {
        int e = e0 + j * BTPB + tid;
        bn[j] = -1;
        if (e < E) {
            int d = e_dst[e];
            int src = e_src[e];
            ushort wb = __half_as_ushort(__float2half_rn(e_w[e]));
            bn[j] = d >> 7;
            pk[j] = ((u64)wb << 48) | ((u64)(unsigned)bn[j] << 33) |
                    ((u64)(unsigned)(d & 127) << 24) | (u64)(unsigned)src;
        }
    }
#pragma unroll
    for (int j = 0; j < EPT; ++j)
        if (bn[j] >= 0) r[j] = atomicAdd(&hist[bn[j]], 1);
    __syncthreads();

    // hierarchical exclusive scan of hist[1024]: 1 bin per thread;
    // wave shfl scan -> 16 wave totals -> wave0 scans totals.
    int lane = tid & 63, wv = tid >> 6;
    int c = hist[tid];
    int s = c;
#pragma unroll
    for (int ofs = 1; ofs < 64; ofs <<= 1) {
        int t = __shfl_up(s, ofs);
        if (lane >= ofs) s += t;
    }
    if (lane == 63) wtot[wv] = s;
    __syncthreads();
    if (tid < 64) {       // wave 0: scan 16 totals, broadcast via LDS
        int v = (tid < 16) ? wtot[tid] : 0;
        int sw = v;
#pragma unroll
        for (int ofs = 1; ofs < 16; ofs <<= 1) {
            int t = __shfl_up(sw, ofs);
            if (tid >= ofs) sw += t;
        }
        if (tid < 16) ((int*)wtot)[tid] = sw - v;   // reuse wtot as wexcl
    }
    __syncthreads();
    int excl = wtot[wv] + (s - c);
    offs[tid] = (ushort)excl;
    __syncthreads();

    // reservation atomic (global, long latency) interleaved with LDS scatter
    {
        int g = c ? atomicAdd(&gcur[tid * GPAD], c) : 0;
        gbase[tid] = (ushort)min(g, CAP);
    }
#pragma unroll
    for (int j = 0; j < EPT; ++j)
        if (bn[j] >= 0) staging[(int)offs[bn[j]] + r[j]] = pk[j];
    __syncthreads();

    // flush: bin-contiguous runs (~8 edges = 64B) -> contiguous global slots
#pragma unroll
    for (int j = 0; j < EPT; ++j) {
        int p = j * BTPB + tid;
        if (p < cc) {
            u64 e = staging[p];
            int bin = (int)((e >> 33) & 1023);
            int pos = (int)gbase[bin] + (p - (int)offs[bin]);
            if (pos < CAP) {
                bucket[(size_t)bin * CAP + pos] =
                    ((e >> 48) << 32) | (e & 0x7FFFFFFFull);
            }
        }
    }
}

// ---- phase 2: counting sort + pair-gather + MFMA + direct store ----
// 1024 threads (16 waves), ~36 KB LDS -> 2 blocks/CU (32 waves), grid 782.
// Wave wv gathers nodes [wv*8, wv*8+8) as 4 pairs: lanes 0-31 node A,
// lanes 32-63 node B, 4 edge-slots/node/step, uint4 loads (8 feats/lane).
// (R15 gather structure; epilogue reduced to MFMA + store via W-folding.)
__global__ __launch_bounds__(1024) void spmm_kernel(
    const ushort* __restrict__ h16, const u64* __restrict__ bucket,
    const int* __restrict__ gcur, const ushort* __restrict__ w16,
    const float* __restrict__ ifeat,
    float* __restrict__ out, int N) {
    __shared__ u64 sorted[CAP];                           // 16 KB
    __shared__ __align__(16) ushort agg16[BINSZ * ASTR];  // 18 KB (f16 agg)
    __shared__ int hist[BINSZ], start[BINSZ];             // 1 KB
    __shared__ int wsum[2];

    int tid = threadIdx.x;
    int bin = blockIdx.x;
    int base = bin << 7;
    int cnt = min(gcur[bin << 4], CAP);
    const u64* bk = bucket + (size_t)bin * CAP;

    if (tid < BINSZ) hist[tid] = 0;
    __syncthreads();

    // single bucket pass: stage entries in regs, rank via atomic-return
    u64 ev0 = 0, ev1 = 0;
    int dl0 = -1, dl1 = -1, r0 = 0, r1 = 0;
    if (tid < cnt) { ev0 = bk[tid]; dl0 = (int)((ev0 >> 24) & 127); }
    if (tid + SPB < cnt) { ev1 = bk[tid + SPB]; dl1 = (int)((ev1 >> 24) & 127); }
    if (dl0 >= 0) r0 = atomicAdd(&hist[dl0], 1);
    if (dl1 >= 0) r1 = atomicAdd(&hist[dl1], 1);
    __syncthreads();

    int lane = tid & 63, wv = tid >> 6;

    // 2-wave shfl exclusive scan over 128 counters
    int sv = 0, vv = 0;
    if (tid < 128) {
        vv = hist[tid];
        sv = vv;
#pragma unroll
        for (int ofs = 1; ofs < 64; ofs <<= 1) {
            int t = __shfl_up(sv, ofs);
            if (lane >= ofs) sv += t;
        }
        if (lane == 63) wsum[tid >> 6] = sv;
    }
    __syncthreads();
    if (tid < 128) start[tid] = sv - vv + ((tid >= 64) ? wsum[0] : 0);
    __syncthreads();

    // scatter into node-sorted LDS (unique slot = start + rank)
    if (dl0 >= 0) sorted[start[dl0] + r0] = ev0;
    if (dl1 >= 0) sorted[start[dl1] + r1] = ev1;
    if (cnt == 0 && tid == 0) sorted[0] = 0;  // finite dummy for clamped reads
    __syncthreads();

    int g8 = lane >> 3;        // 0..7
    int m8 = lane & 7;         // feature block: halves m8*8..m8*8+7
    int hf = g8 >> 2;          // 0: node A (lanes 0-31), 1: node B
    int gs = g8 & 3;           // edge-slot subgroup within node

    // epilogue indices + HOISTED ifeat frag loads (overlap with gather)
    int m = lane & 15, q = lane >> 4;
    int t = wv >> 1, ch = wv & 1;
    f16x8 faI[2];
    {
        const float* ip = ifeat + (size_t)min(base + t * 16 + m, N - 1) * DFEAT;
#pragma unroll
        for (int s = 0; s < 2; ++s) {
            float4 v0 = *(const float4*)(ip + s * 32 + q * 8);
            float4 v1 = *(const float4*)(ip + s * 32 + q * 8 + 4);
            f16x8 tt;
            tt[0] = (_Float16)v0.x; tt[1] = (_Float16)v0.y;
            tt[2] = (_Float16)v0.z; tt[3] = (_Float16)v0.w;
            tt[4] = (_Float16)v1.x; tt[5] = (_Float16)v1.y;
            tt[6] = (_Float16)v1.z; tt[7] = (_Float16)v1.w;
            faI[s] = tt;
        }
    }

    // pair-gather: 4 slots/node/s-step, s unrolled 4 -> 16 slots/node/iter
    for (int kp = 0; kp < 4; ++kp) {
        int nl = (wv << 3) + (kp << 1) + hf;
        int d = hist[nl];
        int b0 = start[nl];
        int hi = (d > 0) ? (b0 + d - 1) : 0;   // clamp target always init'd
        __half2 a0 = u2h(0u), a1 = u2h(0u), a2 = u2h(0u), a3 = u2h(0u);
        for (int t0 = 0; t0 < d; t0 += 16) {
#pragma unroll
            for (int s = 0; s < 4; ++s) {
                int idx = t0 + (s << 2) + gs;
                u64 e = sorted[min(b0 + idx, hi)];
                ushort wb = (idx < d) ? (ushort)(e >> 32) : (ushort)0;
                __half2 w2 = __half2half2(__ushort_as_half(wb));
                unsigned src = ((unsigned)e) & 0x1FFFFu;
                uint4 hv = *(const uint4*)(h16 + ((size_t)src << 6) + (m8 << 3));
                a0 = __hfma2(w2, u2h(hv.x), a0);
                a1 = __hfma2(w2, u2h(hv.y), a1);
                a2 = __hfma2(w2, u2h(hv.z), a2);
                a3 = __hfma2(w2, u2h(hv.w), a3);
            }
        }
        // reduce across the 4 slot-groups (xor 8,16 stay within each half)
        a0 = __hadd2(a0, u2h((unsigned)__shfl_xor((int)h2u(a0), 8)));
        a1 = __hadd2(a1, u2h((unsigned)__shfl_xor((int)h2u(a1), 8)));
        a2 = __hadd2(a2, u2h((unsigned)__shfl_xor((int)h2u(a2), 8)));
        a3 = __hadd2(a3, u2h((unsigned)__shfl_xor((int)h2u(a3), 8)));
        a0 = __hadd2(a0, u2h((unsigned)__shfl_xor((int)h2u(a0), 16)));
        a1 = __hadd2(a1, u2h((unsigned)__shfl_xor((int)h2u(a1), 16)));
        a2 = __hadd2(a2, u2h((unsigned)__shfl_xor((int)h2u(a2), 16)));
        a3 = __hadd2(a3, u2h((unsigned)__shfl_xor((int)h2u(a3), 16)));
        if (gs == 0) {
            uint4 o;
            o.x = h2u(a0); o.y = h2u(a1); o.z = h2u(a2); o.w = h2u(a3);
            *(uint4*)(agg16 + nl * ASTR + (m8 << 3)) = o;
        }
    }
    __syncthreads();   // epilogue tile rows span multiple waves' output

    // fused epilogue: out = [agg, i] @ W'   (mix+residual folded into W')
    f16x8 faA[2];
#pragma unroll
    for (int s = 0; s < 2; ++s)
        faA[s] = *(const f16x8*)(agg16 + (t * 16 + m) * ASTR + s * 32 + q * 8);

    f32x4 acc[2] = {{0.f, 0.f, 0.f, 0.f}, {0.f, 0.f, 0.f, 0.f}};
#pragma unroll
    for (int ci = 0; ci < 2; ++ci) {
        int c = ch * 2 + ci;
#pragma unroll
        for (int s = 0; s < 2; ++s) {
            f16x8 bA = *(const f16x8*)(w16 + ((c * 4 + s) * 64 + lane) * 8);
            acc[ci] = __builtin_amdgcn_mfma_f32_16x16x32_f16(faA[s], bA, acc[ci], 0, 0, 0);
            f16x8 bI = *(const f16x8*)(w16 + ((c * 4 + s + 2) * 64 + lane) * 8);
            acc[ci] = __builtin_amdgcn_mfma_f32_16x16x32_f16(faI[s], bI, acc[ci], 0, 0, 0);
        }
    }

    // direct store (C/D: row = t*16 + q*4 + r, col = c*16 + m)
#pragma unroll
    for (int ci = 0; ci < 2; ++ci) {
        int c = ch * 2 + ci;
        int col = c * 16 + m;
#pragma unroll
        for (int r = 0; r < 4; ++r) {
            int rowL = t * 16 + q * 4 + r;
            int row = base + rowL;
            if (row < N) out[(size_t)row * DFEAT + col] = acc[ci][r];
        }
    }
}

extern "C" void kernel_launch(void* const* d_in, const int* in_sizes, int n_in,
                              void* d_out, int out_size, void* d_ws, size_t ws_size,
                              hipStream_t stream) {
    const float* h       = (const float*)d_in[0];
    const float* ifeat   = (const float*)d_in[1];
    const float* weight  = (const float*)d_in[2];
    const float* edge_w  = (const float*)d_in[3];
    const float* lamda_p = (const float*)d_in[4];
    const float* alpha_p = (const float*)d_in[5];
    const int*   e_src   = (const int*)d_in[6];
    const int*   e_dst   = (const int*)d_in[7];
    const int*   layer_p = (const int*)d_in[8];
    float* out = (float*)d_out;

    int N = in_sizes[0] / DFEAT;       // 100000
    int E = in_sizes[3];               // 1000000
    int nbins = (N + BINSZ - 1) >> 7;  // 782

    // ws: gcur[1024*16] (64KB) | bucket 16.78MB | h16 12.8MB | w16 16KB
    int* gcur = (int*)d_ws;
    u64* bucket = (u64*)((char*)d_ws + (size_t)NBINS * GPAD * sizeof(int));
    ushort* h16 = (ushort*)((char*)bucket + (size_t)NBINS * CAP * sizeof(u64));
    ushort* w16 = h16 + (size_t)N * DFEAT;

    int total4 = N * DFEAT / 4;
    convert_kernel<<<2048, 256, 0, stream>>>(
        h, weight, lamda_p, alpha_p, layer_p, h16, w16, gcur, total4);

    bin_fill_kernel<<<(E + CHUNK - 1) / CHUNK, BTPB, 0, stream>>>(
        e_src, e_dst, edge_w, gcur, bucket, E);

    spmm_kernel<<<nbins, SPB, 0, stream>>>(
        h16, bucket, gcur, w16, ifeat, out, N);
}